// Round 2
// baseline (2025.773 us; speedup 1.0000x reference)
//
#include <hip/hip_runtime.h>
#include <math.h>

typedef unsigned short u16;
typedef unsigned int u32;
typedef __attribute__((ext_vector_type(8))) short short8;
typedef __attribute__((ext_vector_type(4))) float f32x4;

#define EPSQ 1e-5f
#define B_ROWS 41472                 // 512*81 tokens
#define Z_ELEMS ((size_t)B_ROWS * 512)

// ---- bf16 helpers (manual RNE, no hip_bf16 dependency) --------------------
__device__ __forceinline__ u16 f2b(float f) {
  u32 x = __float_as_uint(f);
  u32 r = (x + 0x7fffu + ((x >> 16) & 1u)) >> 16;   // round-to-nearest-even
  return (u16)r;
}
__device__ __forceinline__ float blo(u32 v) { return __uint_as_float(v << 16); }
__device__ __forceinline__ float bhi(u32 v) { return __uint_as_float(v & 0xffff0000u); }
__device__ __forceinline__ u32 pack2(float a, float b) {
  return (u32)f2b(a) | ((u32)f2b(b) << 16);
}

__device__ __forceinline__ float wredMax(float v) {
#pragma unroll
  for (int off = 32; off; off >>= 1) v = fmaxf(v, __shfl_xor(v, off));
  return v;
}
__device__ __forceinline__ float wredSum(float v) {
#pragma unroll
  for (int off = 32; off; off >>= 1) v += __shfl_xor(v, off);
  return v;
}

// ---- weight quantization: per-tensor mean|w| -> ternary ------------------
__global__ __launch_bounds__(256) void wq_sum(const float* __restrict__ w, int n,
                                              float* __restrict__ sum) {
  float acc = 0.f;
  for (int i = blockIdx.x * blockDim.x + threadIdx.x; i < n; i += gridDim.x * blockDim.x)
    acc += fabsf(w[i]);
  acc = wredSum(acc);
  if ((threadIdx.x & 63) == 0) atomicAdd(sum, acc);
}

__global__ __launch_bounds__(256) void wq_quant(const float* __restrict__ w, int n,
                                                const float* __restrict__ sum,
                                                float* __restrict__ mout,
                                                u16* __restrict__ q) {
  const float m = fmaxf(sum[0] / (float)n, EPSQ);   // clip(mean|w|, EPS)
  if (blockIdx.x == 0 && threadIdx.x == 0) mout[0] = m;
  const float s = 1.0f / m;
  for (int i = blockIdx.x * blockDim.x + threadIdx.x; i < n; i += gridDim.x * blockDim.x) {
    float t = rintf(w[i] * s);
    t = fminf(fmaxf(t, -1.f), 1.f);                 // ternary {-1,0,1}
    q[i] = f2b(t);                                  // exact in bf16
  }
}

// ---- act quant of concat([x,y,s]) rows (1536) ----------------------------
__global__ __launch_bounds__(256) void aq_concat(const float* __restrict__ x,
                                                 const float* __restrict__ y,
                                                 const float* __restrict__ s,
                                                 u16* __restrict__ qx,
                                                 float* __restrict__ dsc, int row0) {
  const int r = blockIdx.x;
  const size_t R = (size_t)(row0 + r);
  const int t = threadIdx.x;
  float2 vx = *(const float2*)(x + R * 512 + t * 2);
  float2 vy = *(const float2*)(y + R * 512 + t * 2);
  float2 vs = *(const float2*)(s + R * 512 + t * 2);
  float mx = fmaxf(fmaxf(fabsf(vx.x), fabsf(vx.y)),
                   fmaxf(fmaxf(fabsf(vy.x), fabsf(vy.y)), fmaxf(fabsf(vs.x), fabsf(vs.y))));
  mx = wredMax(mx);
  __shared__ float red[4];
  if ((t & 63) == 0) red[t >> 6] = mx;
  __syncthreads();
  mx = fmaxf(fmaxf(red[0], red[1]), fmaxf(red[2], red[3]));
  const float m = fmaxf(mx, EPSQ);
  const float scq = 127.f / m;
  if (t == 0) dsc[r] = m * (1.f / 127.f);
  u16* qrow = qx + (size_t)r * 1536;
#define QZ(v) fminf(fmaxf(rintf((v) * scq), -128.f), 127.f)
  *(u32*)&qrow[t * 2] = pack2(QZ(vx.x), QZ(vx.y));
  *(u32*)&qrow[512 + t * 2] = pack2(QZ(vy.x), QZ(vy.y));
  *(u32*)&qrow[1024 + t * 2] = pack2(QZ(vs.x), QZ(vs.y));
#undef QZ
}

// ---- act quant of f32 rows of 512 (one wave per row) ---------------------
__global__ __launch_bounds__(256) void aq_row512(const float* __restrict__ src,
                                                 u16* __restrict__ q,
                                                 float* __restrict__ dsc) {
  const int row = blockIdx.x * 4 + (threadIdx.x >> 6);
  const int l = threadIdx.x & 63;
  const float* pr = src + (size_t)row * 512 + l * 8;
  float4 v0 = *(const float4*)pr;
  float4 v1 = *(const float4*)(pr + 4);
  float mx = fmaxf(fmaxf(fmaxf(fabsf(v0.x), fabsf(v0.y)), fmaxf(fabsf(v0.z), fabsf(v0.w))),
                   fmaxf(fmaxf(fabsf(v1.x), fabsf(v1.y)), fmaxf(fabsf(v1.z), fabsf(v1.w))));
  mx = wredMax(mx);
  const float m = fmaxf(mx, EPSQ);
  const float scq = 127.f / m;
  if (l == 0) dsc[row] = m * (1.f / 127.f);
#define QZ(v) fminf(fmaxf(rintf((v) * scq), -128.f), 127.f)
  uint4 o = make_uint4(pack2(QZ(v0.x), QZ(v0.y)), pack2(QZ(v0.z), QZ(v0.w)),
                       pack2(QZ(v1.x), QZ(v1.y)), pack2(QZ(v1.z), QZ(v1.w)));
#undef QZ
  *(uint4*)(q + (size_t)row * 512 + l * 8) = o;
}

// ---- act quant of bf16 rows of 2048 (one block per row) ------------------
__global__ __launch_bounds__(256) void aq_row2048(const u16* __restrict__ g,
                                                  u16* __restrict__ qg,
                                                  float* __restrict__ dsc) {
  const int r = blockIdx.x, t = threadIdx.x;
  uint4 raw = *(const uint4*)(g + (size_t)r * 2048 + t * 8);
  float f[8] = {blo(raw.x), bhi(raw.x), blo(raw.y), bhi(raw.y),
                blo(raw.z), bhi(raw.z), blo(raw.w), bhi(raw.w)};
  float mx = 0.f;
#pragma unroll
  for (int i = 0; i < 8; ++i) mx = fmaxf(mx, fabsf(f[i]));
  mx = wredMax(mx);
  __shared__ float red[4];
  if ((t & 63) == 0) red[t >> 6] = mx;
  __syncthreads();
  mx = fmaxf(fmaxf(red[0], red[1]), fmaxf(red[2], red[3]));
  const float m = fmaxf(mx, EPSQ);
  const float scq = 127.f / m;
  if (t == 0) dsc[r] = m * (1.f / 127.f);
#define QZ(v) fminf(fmaxf(rintf((v) * scq), -128.f), 127.f)
  uint4 o = make_uint4(pack2(QZ(f[0]), QZ(f[1])), pack2(QZ(f[2]), QZ(f[3])),
                       pack2(QZ(f[4]), QZ(f[5])), pack2(QZ(f[6]), QZ(f[7])));
#undef QZ
  *(uint4*)(qg + (size_t)r * 2048 + t * 8) = o;
}

// ---- sigmoid mask head: dot(row512, w) -> f32 ----------------------------
__global__ __launch_bounds__(256) void bit_mask(const u16* __restrict__ qh,
                                                const float* __restrict__ dsc,
                                                const u16* __restrict__ qwm,
                                                const float* __restrict__ mWp,
                                                float* __restrict__ outp) {
  const int row = blockIdx.x * 4 + (threadIdx.x >> 6);
  const int l = threadIdx.x & 63;
  uint4 av = *(const uint4*)(qh + (size_t)row * 512 + l * 8);
  uint4 wv = *(const uint4*)(qwm + l * 8);
  float acc = blo(av.x) * blo(wv.x) + bhi(av.x) * bhi(wv.x) +
              blo(av.y) * blo(wv.y) + bhi(av.y) * bhi(wv.y) +
              blo(av.z) * blo(wv.z) + bhi(av.z) * bhi(wv.z) +
              blo(av.w) * blo(wv.w) + bhi(av.w) * bhi(wv.w);
  acc = wredSum(acc);
  if (l == 0) {
    float v = acc * dsc[row] * mWp[0];
    outp[row] = 1.f / (1.f + expf(-v));
  }
}

// ---- GEMM: C[M,N] = (A[M,K] @ W[N,K]^T) * dA[row] * mW, bf16-int MFMA ----
// EPI: 0 = f32 store, 1 = exact-gelu -> bf16 store, 2 = f32 += (residual)
template <int EPI>
__global__ __launch_bounds__(256) void gemm_bt(const u16* __restrict__ A,
                                               const u16* __restrict__ Bw,
                                               const float* __restrict__ dA,
                                               const float* __restrict__ mWp,
                                               float* __restrict__ Cf,
                                               u16* __restrict__ Cb,
                                               int N, int K, int ldc) {
  __shared__ u16 lA[128 * 64];
  __shared__ u16 lB[128 * 64];
  const int tilesN = N >> 7;
  const int tm = blockIdx.x / tilesN, tn = blockIdx.x - tm * tilesN;
  const int t = threadIdx.x;
  const int w = t >> 6, l = t & 63;
  const int wr = w >> 1, wc = w & 1;   // 2x2 waves, each 64x64
  const int lq = l >> 4, lr = l & 15;

  f32x4 zero = {0.f, 0.f, 0.f, 0.f};
  f32x4 acc[4][4];
#pragma unroll
  for (int m = 0; m < 4; ++m)
#pragma unroll
    for (int n = 0; n < 4; ++n) acc[m][n] = zero;

  const int srow = t >> 3;             // 0..31 staging row
  const int scb = t & 7;               // 16B column block
  const size_t Abase = (size_t)(tm * 128 + srow) * K + scb * 8;
  const size_t Bbase = (size_t)(tn * 128 + srow) * K + scb * 8;

  for (int k0 = 0; k0 < K; k0 += 64) {
    int4 ra[4], rb[4];
#pragma unroll
    for (int r = 0; r < 4; ++r) {
      ra[r] = *(const int4*)(A + Abase + (size_t)r * 32 * K + k0);
      rb[r] = *(const int4*)(Bw + Bbase + (size_t)r * 32 * K + k0);
    }
    __syncthreads();                   // previous tile fully consumed
#pragma unroll
    for (int r = 0; r < 4; ++r) {      // XOR-swizzled LDS write (T2)
      int row = r * 32 + srow;
      *(int4*)&lA[row * 64 + ((scb ^ (row & 7)) << 3)] = ra[r];
      *(int4*)&lB[row * 64 + ((scb ^ (row & 7)) << 3)] = rb[r];
    }
    __syncthreads();
#pragma unroll
    for (int kk = 0; kk < 2; ++kk) {
      short8 av[4], bv[4];
#pragma unroll
      for (int m = 0; m < 4; ++m) {
        int row = wr * 64 + m * 16 + lr;
        av[m] = *(const short8*)&lA[row * 64 + (((kk * 4 + lq) ^ (row & 7)) << 3)];
      }
#pragma unroll
      for (int n = 0; n < 4; ++n) {
        int row = wc * 64 + n * 16 + lr;
        bv[n] = *(const short8*)&lB[row * 64 + (((kk * 4 + lq) ^ (row & 7)) << 3)];
      }
#pragma unroll
      for (int m = 0; m < 4; ++m)
#pragma unroll
        for (int n = 0; n < 4; ++n)
          acc[m][n] = __builtin_amdgcn_mfma_f32_16x16x32_bf16(av[m], bv[n], acc[m][n], 0, 0, 0);
    }
  }

  const float mw = mWp[0];
#pragma unroll
  for (int m = 0; m < 4; ++m) {
#pragma unroll
    for (int r = 0; r < 4; ++r) {
      const int row = tm * 128 + wr * 64 + m * 16 + lq * 4 + r;
      const float sc = dA[row] * mw;
#pragma unroll
      for (int n = 0; n < 4; ++n) {
        const int col = tn * 128 + wc * 64 + n * 16 + lr;
        float v = acc[m][n][r] * sc;
        if constexpr (EPI == 0) {
          Cf[(size_t)row * ldc + col] = v;
        } else if constexpr (EPI == 1) {
          v = 0.5f * v * (1.f + erff(v * 0.70710678f));   // exact gelu
          Cb[(size_t)row * ldc + col] = f2b(v);
        } else {
          size_t ix = (size_t)row * ldc + col;
          Cf[ix] += v;                                    // residual add
        }
      }
    }
  }
}

extern "C" void kernel_launch(void* const* d_in, const int* in_sizes, int n_in,
                              void* d_out, int out_size, void* d_ws, size_t ws_size,
                              hipStream_t stream) {
  const float* x = (const float*)d_in[0];
  const float* y = (const float*)d_in[1];
  const float* sp = (const float*)d_in[2];
  const float* Win = (const float*)d_in[3];
  const float* Wf1 = (const float*)d_in[4];
  const float* Wf2 = (const float*)d_in[5];
  const float* Wz = (const float*)d_in[6];
  const float* Wm = (const float*)d_in[7];
  float* out = (float*)d_out;          // f32 outputs (reference returns float32)

  const int TILES = B_ROWS / 128;     // 324
  char* p = (char*)d_ws;
  float* wsum = (float*)p; p += 256;
  float* mW = (float*)p; p += 256;
  u16* qWin = (u16*)p; p += (size_t)512 * 1536 * 2;
  u16* qWf1 = (u16*)p; p += (size_t)2048 * 512 * 2;
  u16* qWf2 = (u16*)p; p += (size_t)512 * 2048 * 2;
  u16* qWz = (u16*)p; p += (size_t)512 * 512 * 2;
  u16* qWm = (u16*)p; p += 1024;
  const size_t fixedB = (size_t)(p - (char*)d_ws);

  // choose largest M-chunk that fits ws (bytes/row = 14352)
  int Tc = 1;
  for (int nch = 1; nch <= TILES; ++nch) {
    int tc = (TILES + nch - 1) / nch;
    if (fixedB + (size_t)tc * 128 * 14352 + 1024 <= ws_size) { Tc = tc; break; }
  }
  const size_t McMax = (size_t)Tc * 128;
  u16* qx = (u16*)p; p += McMax * 1536 * 2;
  float* h = (float*)p; p += McMax * 512 * 4;
  u16* qh = (u16*)p; p += McMax * 512 * 2;
  u16* g = (u16*)p; p += McMax * 2048 * 2;
  u16* qg = (u16*)p; p += McMax * 2048 * 2;
  float* d1 = (float*)p; p += McMax * 4;
  float* d2 = (float*)p; p += McMax * 4;
  float* dgs = (float*)p; p += McMax * 4;
  float* d3 = (float*)p; p += McMax * 4;

  hipMemsetAsync(wsum, 0, 8 * sizeof(float), stream);
  wq_sum<<<64, 256, 0, stream>>>(Win, 512 * 1536, wsum + 0);
  wq_sum<<<64, 256, 0, stream>>>(Wf1, 2048 * 512, wsum + 1);
  wq_sum<<<64, 256, 0, stream>>>(Wf2, 512 * 2048, wsum + 2);
  wq_sum<<<64, 256, 0, stream>>>(Wz, 512 * 512, wsum + 3);
  wq_sum<<<8, 256, 0, stream>>>(Wm, 512, wsum + 4);
  wq_quant<<<64, 256, 0, stream>>>(Win, 512 * 1536, wsum + 0, mW + 0, qWin);
  wq_quant<<<64, 256, 0, stream>>>(Wf1, 2048 * 512, wsum + 1, mW + 1, qWf1);
  wq_quant<<<64, 256, 0, stream>>>(Wf2, 512 * 2048, wsum + 2, mW + 2, qWf2);
  wq_quant<<<16, 256, 0, stream>>>(Wz, 512 * 512, wsum + 3, mW + 3, qWz);
  wq_quant<<<2, 256, 0, stream>>>(Wm, 512, wsum + 4, mW + 4, qWm);

  for (int c0 = 0; c0 < TILES; c0 += Tc) {
    const int tiles = (TILES - c0 < Tc) ? (TILES - c0) : Tc;
    const int Mc = tiles * 128;
    const int row0 = c0 * 128;
    aq_concat<<<Mc, 256, 0, stream>>>(x, y, sp, qx, d1, row0);
    gemm_bt<0><<<tiles * 4, 256, 0, stream>>>(qx, qWin, d1, mW + 0, h, nullptr, 512, 1536, 512);
    aq_row512<<<Mc / 4, 256, 0, stream>>>(h, qh, d2);
    gemm_bt<1><<<tiles * 16, 256, 0, stream>>>(qh, qWf1, d2, mW + 1, nullptr, g, 2048, 512, 2048);
    aq_row2048<<<Mc, 256, 0, stream>>>(g, qg, dgs);
    gemm_bt<2><<<tiles * 4, 256, 0, stream>>>(qg, qWf2, dgs, mW + 2, h, nullptr, 512, 2048, 512);
    aq_row512<<<Mc / 4, 256, 0, stream>>>(h, qh, d3);
    gemm_bt<0><<<tiles * 4, 256, 0, stream>>>(qh, qWz, d3, mW + 3, out + (size_t)row0 * 512,
                                              nullptr, 512, 512, 512);
    bit_mask<<<Mc / 4, 256, 0, stream>>>(qh, d3, qWm, mW + 4, out + Z_ELEMS + row0);
  }
}